// Round 9
// baseline (644.847 us; speedup 1.0000x reference)
//
#include <hip/hip_runtime.h>
#include <hip/hip_bf16.h>

#define NN 100000   // nodes
#define NE 1600000  // edges
#define NG 1000     // graphs
#define NBK 196     // dst buckets of 512 nodes (196*512 >= NN)
#define BSH 9       // bucket shift
#define SLOT 10240  // slack region per bucket (mean 8192 + 4-align padding)

typedef short short8 __attribute__((ext_vector_type(8)));
typedef float f32x4 __attribute__((ext_vector_type(4)));

static inline int cdiv(int a, int b) { return (a + b - 1) / b; }

// f32 -> bf16 (RNE) and helpers
__device__ __forceinline__ unsigned short f2b(float f) {
    unsigned int u = __float_as_uint(f);
    u += 0x7fff + ((u >> 16) & 1);
    return (unsigned short)(u >> 16);
}
__device__ __forceinline__ unsigned int pack2(float lo, float hi) {
    return (unsigned int)f2b(lo) | ((unsigned int)f2b(hi) << 16);
}
__device__ __forceinline__ float bf_lo(unsigned int v) { return __uint_as_float(v << 16); }
__device__ __forceinline__ float bf_hi(unsigned int v) { return __uint_as_float(v & 0xffff0000u); }

// ------------------------------------------------- prep: W transpose + cursor init
__global__ __launch_bounds__(256) void k_prep(const float* __restrict__ W1,
                                              const float* __restrict__ W2,
                                              unsigned short* __restrict__ Wt1,
                                              unsigned short* __restrict__ Wt2,
                                              int* __restrict__ gcur) {
    int b = blockIdx.x, t = threadIdx.x;
    if (b < 128) {
        if (t < 128) Wt1[b * 128 + t] = f2b(W1[t * 128 + b]);
        else         Wt2[b * 128 + (t - 128)] = f2b(W2[(t - 128) * 128 + b]);
    } else if (t < NBK) {
        gcur[t] = t * SLOT;
    }
}

// -------------------------------------------------------- two-phase binning
__global__ __launch_bounds__(256) void k_bin2(const int* __restrict__ row,
                                              const int* __restrict__ col,
                                              int* __restrict__ gcur,
                                              unsigned int* __restrict__ tmp) {
    __shared__ int cnt[NBK];
    __shared__ int gbase[NBK];
    int t = threadIdx.x;
    if (t < NBK) cnt[t] = 0;
    __syncthreads();
    const int q0 = blockIdx.x * 1000;  // int4 index base (4000 edges)
    const int4* col4 = (const int4*)col;
    const int4* row4 = (const int4*)row;
#pragma unroll
    for (int it = 0; it < 4; it++) {
        int idx = it * 256 + t;
        if (idx < 1000) {
            int4 c = col4[q0 + idx];
            atomicAdd(&cnt[c.x >> BSH], 1);
            atomicAdd(&cnt[c.y >> BSH], 1);
            atomicAdd(&cnt[c.z >> BSH], 1);
            atomicAdd(&cnt[c.w >> BSH], 1);
        }
    }
    __syncthreads();
    if (t < NBK) {
        gbase[t] = atomicAdd(&gcur[t], cnt[t]);
        cnt[t] = 0;  // becomes local cursor
    }
    __syncthreads();
#pragma unroll
    for (int it = 0; it < 4; it++) {
        int idx = it * 256 + t;
        if (idx < 1000) {
            int4 c = col4[q0 + idx];
            int4 r = row4[q0 + idx];
            int d, s, b, p;
            d = c.x; s = r.x; b = d >> BSH; p = atomicAdd(&cnt[b], 1);
            tmp[gbase[b] + p] = ((unsigned int)(d & 511) << 17) | (unsigned int)s;
            d = c.y; s = r.y; b = d >> BSH; p = atomicAdd(&cnt[b], 1);
            tmp[gbase[b] + p] = ((unsigned int)(d & 511) << 17) | (unsigned int)s;
            d = c.z; s = r.z; b = d >> BSH; p = atomicAdd(&cnt[b], 1);
            tmp[gbase[b] + p] = ((unsigned int)(d & 511) << 17) | (unsigned int)s;
            d = c.w; s = r.w; b = d >> BSH; p = atomicAdd(&cnt[b], 1);
            tmp[gbase[b] + p] = ((unsigned int)(d & 511) << 17) | (unsigned int)s;
        }
    }
}

// -------------------------------------------------------- per-bucket CSR
__global__ __launch_bounds__(256) void k_bucket(const unsigned int* __restrict__ tmp,
                                                const int* __restrict__ gcur,
                                                int* __restrict__ off,
                                                int* __restrict__ degw,
                                                float* __restrict__ dinv,
                                                int* __restrict__ csr_src) {
    __shared__ int cnt[512];
    __shared__ int loff[512];
    __shared__ int sh[256];
    int b = blockIdx.x, t = threadIdx.x;
    int j0 = b << BSH;
    int nd = min(512, NN - j0);
    int rb = b * SLOT;
    int m = gcur[b] - rb;
    cnt[t] = 0; cnt[t + 256] = 0;
    __syncthreads();
    for (int i = t; i < m; i += 256)
        atomicAdd(&cnt[tmp[rb + i] >> 17], 1);
    __syncthreads();
    int r0 = cnt[2 * t], r1 = cnt[2 * t + 1];
    int p0 = (r0 + 3) & ~3, p1 = (r1 + 3) & ~3;  // pad to 4-entry alignment
    int ts = p0 + p1;
    sh[t] = ts;
    __syncthreads();
    for (int d = 1; d < 256; d <<= 1) {
        int u = (t >= d) ? sh[t - d] : 0;
        __syncthreads();
        sh[t] += u;
        __syncthreads();
    }
    int ex = sh[t] - ts;
    loff[2 * t] = ex;
    loff[2 * t + 1] = ex + p0;
    __syncthreads();
    for (int j = t; j < nd; j += 256) {
        int o = rb + loff[j];
        int dg = cnt[j];
        off[j0 + j] = o;
        degw[j0 + j] = dg;
        dinv[j0 + j] = rsqrtf((float)(dg + 1));  // +1 self-loop
        cnt[j] = o;  // becomes cursor
    }
    __syncthreads();
    for (int i = t; i < m; i += 256) {
        unsigned int e = tmp[rb + i];
        int d = e >> 17;
        int s = (int)(e & 0x1FFFFu);
        int p = atomicAdd(&cnt[d], 1);
        csr_src[p] = s;
    }
}

// ---------------------------------------------------------------- MFMA GEMM
// Hs_sl[c/16][r][c%16] = bf16( dinv[r] * sum_k A[r][k] * Wt[c][k] )
// Output COLUMN-SLICED: 8 slices of 16 cols (32B/row) for XCD-local gathers.
// ASL: A also sliced (layer 2); else A is f32 row-major (layer-1 input x).
template <bool ASL>
__global__ __launch_bounds__(256) void k_gemm(const void* __restrict__ Ap,
                                              const unsigned short* __restrict__ Wt,
                                              const float* __restrict__ dinv,
                                              unsigned short* __restrict__ Hs) {
    __shared__ __align__(16) unsigned short Ws[128 * 128];  // 32 KB
    int t = threadIdx.x;
#pragma unroll
    for (int i = 0; i < 8; i++) {
        int id = t + i * 256;
        int n = id >> 4, c = id & 15;
        *(short8*)((char*)Ws + n * 256 + ((c ^ (n & 15)) << 4)) =
            *(const short8*)(Wt + n * 128 + c * 8);
    }
    __syncthreads();

    int lane = t & 63, wid = t >> 6;
    int n16 = lane & 15, quad = lane >> 4;
    int row_base = blockIdx.x * 128 + wid * 32;

    short8 a[2][4];
#pragma unroll
    for (int rt = 0; rt < 2; rt++) {
        int r = row_base + rt * 16 + n16;
        if (r > NN - 1) r = NN - 1;
        if (!ASL) {
            const float* ap = (const float*)Ap + (size_t)r * 128 + quad * 8;
#pragma unroll
            for (int ks = 0; ks < 4; ks++) {
                float4 v0 = *(const float4*)(ap + ks * 32);
                float4 v1 = *(const float4*)(ap + ks * 32 + 4);
                uint4 up;
                up.x = pack2(v0.x, v0.y); up.y = pack2(v0.z, v0.w);
                up.z = pack2(v1.x, v1.y); up.w = pack2(v1.z, v1.w);
                a[rt][ks] = *(short8*)&up;
            }
        } else {
            // sliced A: col = ks*32 + quad*8 -> slice 2ks+(quad>>1), offset (quad&1)*8
            const unsigned short* ab = (const unsigned short*)Ap;
#pragma unroll
            for (int ks = 0; ks < 4; ks++) {
                int sl = 2 * ks + (quad >> 1);
                a[rt][ks] = *(const short8*)(ab + (size_t)sl * NN * 16 + r * 16 + (quad & 1) * 8);
            }
        }
    }

    f32x4 acc[2][8];
#pragma unroll
    for (int rt = 0; rt < 2; rt++)
#pragma unroll
        for (int ct = 0; ct < 8; ct++)
            acc[rt][ct] = (f32x4){0.f, 0.f, 0.f, 0.f};

#pragma unroll
    for (int ks = 0; ks < 4; ks++) {
#pragma unroll
        for (int ct = 0; ct < 8; ct++) {
            short8 b = *(const short8*)((const char*)Ws +
                        (ct * 16 + n16) * 256 + ((((ks << 2) + quad) ^ n16) << 4));
            acc[0][ct] = __builtin_amdgcn_mfma_f32_16x16x32_bf16(a[0][ks], b, acc[0][ct], 0, 0, 0);
            acc[1][ct] = __builtin_amdgcn_mfma_f32_16x16x32_bf16(a[1][ks], b, acc[1][ct], 0, 0, 0);
        }
    }

    // epilogue: D[row=quad*4+reg][col=ct*16+n16] -> sliced store (slice=ct)
#pragma unroll
    for (int rt = 0; rt < 2; rt++) {
#pragma unroll
        for (int reg = 0; reg < 4; reg++) {
            int row = row_base + rt * 16 + quad * 4 + reg;
            if (row < NN) {
                float di = dinv[row];
#pragma unroll
                for (int ct = 0; ct < 8; ct++)
                    Hs[(size_t)ct * NN * 16 + row * 16 + n16] = f2b(acc[rt][ct][reg] * di);
            }
        }
    }
}

// ---------------------------------------------------------------- aggregation
// slice = blockIdx%8 (XCD-affine under round-robin dispatch): each XCD's
// gather working set is one 3.2MB slice -> L2-resident.
// wave = 1 node; 8 subgroups x 8 lanes; subgroup handles one edge (uint/lane).
__global__ __launch_bounds__(256) void k_agg(const unsigned short* __restrict__ Hsb,
                                             const int* __restrict__ off,
                                             const int* __restrict__ degw,
                                             const int* __restrict__ csr_src,
                                             const float* __restrict__ dinv,
                                             const float* __restrict__ bias,
                                             unsigned short* __restrict__ outb) {
    int s = blockIdx.x & 7;
    int node = (blockIdx.x >> 3) * 4 + (threadIdx.x >> 6);
    int lane = threadIdx.x & 63;
    int sub = lane >> 3, li = lane & 7;
    const unsigned int* H = (const unsigned int*)(Hsb + (size_t)s * NN * 16);  // uint = 2 cols
    float ax = 0.f, ay = 0.f;
    if (sub == 0) {  // self term (already dinv-scaled)
        unsigned int v = H[node * 8 + li];
        ax = bf_lo(v); ay = bf_hi(v);
    }
    int e0 = off[node], e1 = e0 + degw[node];
    int e = e0;
    for (; e + 16 <= e1; e += 16) {
        int sA = csr_src[e + sub];
        int sB = csr_src[e + 8 + sub];
        unsigned int wA = H[sA * 8 + li];
        unsigned int wB = H[sB * 8 + li];
        ax += bf_lo(wA) + bf_lo(wB);
        ay += bf_hi(wA) + bf_hi(wB);
    }
    for (; e < e1; e += 8) {
        int ee = e + sub;
        if (ee < e1) {
            int sA = csr_src[ee];
            unsigned int w = H[sA * 8 + li];
            ax += bf_lo(w);
            ay += bf_hi(w);
        }
    }
#pragma unroll
    for (int d = 8; d <= 32; d <<= 1) {
        ax += __shfl_xor(ax, d);
        ay += __shfl_xor(ay, d);
    }
    if (sub == 0) {
        float di = dinv[node];
        float2 b = *(const float2*)(bias + s * 16 + li * 2);
        float r0 = fmaxf(fmaf(di, ax, b.x), 0.f);
        float r1 = fmaxf(fmaf(di, ay, b.y), 0.f);
        ((unsigned int*)(outb + (size_t)s * NN * 16))[node * 8 + li] = pack2(r0, r1);
    }
}

// ------------------------------------------------- fused mean-pool + head MLP
// reads sliced activations: col li*8 -> slice li>>1, offset (li&1)*8
__global__ __launch_bounds__(256) void k_poolhead(const unsigned short* __restrict__ A,
                                                  const int* __restrict__ batch,
                                                  const float* __restrict__ u,
                                                  const float* __restrict__ Wh1,
                                                  const float* __restrict__ bh1,
                                                  const float* __restrict__ Wh2,
                                                  const float* __restrict__ bh2,
                                                  float* __restrict__ out) {
    int g = blockIdx.x, t = threadIdx.x;
    int lo = 0, hi = NN;
    while (lo < hi) { int m = (lo + hi) >> 1; if (batch[m] < g) lo = m + 1; else hi = m; }
    int start = lo;
    hi = NN;
    while (lo < hi) { int m = (lo + hi) >> 1; if (batch[m] < g + 1) lo = m + 1; else hi = m; }
    int end = lo;

    int li = t & 15;   // col chunk (8 cols)
    int ri = t >> 4;   // row offset 0..15
    const unsigned short* Ab = A + (size_t)(li >> 1) * NN * 16 + (li & 1) * 8;
    float acc[8] = {0.f, 0.f, 0.f, 0.f, 0.f, 0.f, 0.f, 0.f};
    for (int i = start + ri; i < end; i += 16) {
        uint4 v = *(const uint4*)(Ab + (size_t)i * 16);
        acc[0] += bf_lo(v.x); acc[1] += bf_hi(v.x);
        acc[2] += bf_lo(v.y); acc[3] += bf_hi(v.y);
        acc[4] += bf_lo(v.z); acc[5] += bf_hi(v.z);
        acc[6] += bf_lo(v.w); acc[7] += bf_hi(v.w);
    }
#pragma unroll
    for (int j = 0; j < 8; j++) {
        acc[j] += __shfl_xor(acc[j], 16);
        acc[j] += __shfl_xor(acc[j], 32);
    }
    __shared__ float part[4][128];
    __shared__ float hc[192];
    __shared__ float tt[128];
    int w = t >> 6;
    if ((t & 63) < 16) {
#pragma unroll
        for (int j = 0; j < 8; j++) part[w][li * 8 + j] = acc[j];
    }
    __syncthreads();
    float cntf = (float)max(end - start, 1);
    if (t < 128) {
        hc[t] = (part[0][t] + part[1][t] + part[2][t] + part[3][t]) / cntf;
    } else if (t < 192) {
        hc[t] = u[g * 64 + (t - 128)];
    }
    __syncthreads();
    if (t < 128) {
        float a2 = bh1[t];
        for (int k = 0; k < 192; k++) a2 = fmaf(hc[k], Wh1[k * 128 + t], a2);
        tt[t] = fmaxf(a2, 0.f);
    }
    __syncthreads();
    if (t < 2) {
        float o = bh2[t];
        for (int c2 = 0; c2 < 128; c2++) o = fmaf(tt[c2], Wh2[c2 * 2 + t], o);
        out[g * 2 + t] = o;
    }
}

// ---------------------------------------------------------------- launcher
extern "C" void kernel_launch(void* const* d_in, const int* in_sizes, int n_in,
                              void* d_out, int out_size, void* d_ws, size_t ws_size,
                              hipStream_t stream) {
    const float* x   = (const float*)d_in[0];
    const int*   ei  = (const int*)d_in[1];
    const int*   row = ei;        // edge_index[0] = src
    const int*   col = ei + NE;   // edge_index[1] = dst
    const float* u   = (const float*)d_in[2];
    const int*   batch = (const int*)d_in[3];
    const float* W1  = (const float*)d_in[5];
    const float* b1  = (const float*)d_in[6];
    const float* W2  = (const float*)d_in[7];
    const float* b2  = (const float*)d_in[8];
    const float* Wh1 = (const float*)d_in[9];
    const float* bh1 = (const float*)d_in[10];
    const float* Wh2 = (const float*)d_in[11];
    const float* bh2 = (const float*)d_in[12];
    float* out = (float*)d_out;

    char* ws = (char*)d_ws;
    size_t o = 0;
    auto alloc = [&](size_t bytes) -> void* {
        void* p = ws + o;
        o += (bytes + 511) & ~(size_t)511;
        return p;
    };
    unsigned short* Hsb = (unsigned short*)alloc((size_t)NN * 128 * 2);
    unsigned short* A1b = (unsigned short*)alloc((size_t)NN * 128 * 2);
    unsigned short* A2b = (unsigned short*)alloc((size_t)NN * 128 * 2);
    unsigned short* Wt1 = (unsigned short*)alloc((size_t)128 * 128 * 2);
    unsigned short* Wt2 = (unsigned short*)alloc((size_t)128 * 128 * 2);
    float* dinv   = (float*)alloc((size_t)NN * 4);
    int*   off    = (int*)alloc((size_t)NN * 4);
    int*   degw   = (int*)alloc((size_t)NN * 4);
    int*   csr_src= (int*)alloc((size_t)NBK * SLOT * 4);
    unsigned int* tmp = (unsigned int*)alloc((size_t)NBK * SLOT * 4);
    int*   gcur   = (int*)alloc((size_t)256 * 4);

    // --- prep (W transpose + cursors) & CSR build ---
    k_prep<<<129, 256, 0, stream>>>(W1, W2, Wt1, Wt2, gcur);
    k_bin2<<<400, 256, 0, stream>>>(row, col, gcur, tmp);
    k_bucket<<<NBK, 256, 0, stream>>>(tmp, gcur, off, degw, dinv, csr_src);

    // --- layer 1 (f32 input) ---
    k_gemm<false><<<cdiv(NN, 128), 256, 0, stream>>>((const void*)x, Wt1, dinv, Hsb);
    k_agg<<<(NN / 4) * 8, 256, 0, stream>>>(Hsb, off, degw, csr_src, dinv, b1, A1b);
    // --- layer 2 (sliced input) ---
    k_gemm<true><<<cdiv(NN, 128), 256, 0, stream>>>((const void*)A1b, Wt2, dinv, Hsb);
    k_agg<<<(NN / 4) * 8, 256, 0, stream>>>(Hsb, off, degw, csr_src, dinv, b2, A2b);

    // --- fused mean pool + head ---
    k_poolhead<<<NG, 256, 0, stream>>>(A2b, batch, u, Wh1, bh1, Wh2, bh2, out);
}

// Round 10
// 333.942 us; speedup vs baseline: 1.9310x; 1.9310x over previous
//
#include <hip/hip_runtime.h>
#include <hip/hip_bf16.h>

#define NN 100000   // nodes
#define NE 1600000  // edges
#define NG 1000     // graphs
#define NBK 196     // dst buckets of 512 nodes (196*512 >= NN)
#define BSH 9       // bucket shift
#define SLOT 10240  // slack region per bucket (mean 8192 + 4-align padding)

typedef short short8 __attribute__((ext_vector_type(8)));
typedef float f32x4 __attribute__((ext_vector_type(4)));

static inline int cdiv(int a, int b) { return (a + b - 1) / b; }

// f32 -> bf16 (RNE) and helpers
__device__ __forceinline__ unsigned short f2b(float f) {
    unsigned int u = __float_as_uint(f);
    u += 0x7fff + ((u >> 16) & 1);
    return (unsigned short)(u >> 16);
}
__device__ __forceinline__ unsigned int pack2(float lo, float hi) {
    return (unsigned int)f2b(lo) | ((unsigned int)f2b(hi) << 16);
}
__device__ __forceinline__ float bf_lo(unsigned int v) { return __uint_as_float(v << 16); }
__device__ __forceinline__ float bf_hi(unsigned int v) { return __uint_as_float(v & 0xffff0000u); }

// ------------------------------------------------- prep: W transpose + cursor init
__global__ __launch_bounds__(256) void k_prep(const float* __restrict__ W1,
                                              const float* __restrict__ W2,
                                              unsigned short* __restrict__ Wt1,
                                              unsigned short* __restrict__ Wt2,
                                              int* __restrict__ gcur) {
    int b = blockIdx.x, t = threadIdx.x;
    if (b < 128) {
        if (t < 128) Wt1[b * 128 + t] = f2b(W1[t * 128 + b]);
        else         Wt2[b * 128 + (t - 128)] = f2b(W2[(t - 128) * 128 + b]);
    } else if (t < NBK) {
        gcur[t] = t * SLOT;
    }
}

// -------------------------------------------------------- two-phase binning
__global__ __launch_bounds__(256) void k_bin2(const int* __restrict__ row,
                                              const int* __restrict__ col,
                                              int* __restrict__ gcur,
                                              unsigned int* __restrict__ tmp) {
    __shared__ int cnt[NBK];
    __shared__ int gbase[NBK];
    int t = threadIdx.x;
    if (t < NBK) cnt[t] = 0;
    __syncthreads();
    const int q0 = blockIdx.x * 1000;  // int4 index base (4000 edges)
    const int4* col4 = (const int4*)col;
    const int4* row4 = (const int4*)row;
#pragma unroll
    for (int it = 0; it < 4; it++) {
        int idx = it * 256 + t;
        if (idx < 1000) {
            int4 c = col4[q0 + idx];
            atomicAdd(&cnt[c.x >> BSH], 1);
            atomicAdd(&cnt[c.y >> BSH], 1);
            atomicAdd(&cnt[c.z >> BSH], 1);
            atomicAdd(&cnt[c.w >> BSH], 1);
        }
    }
    __syncthreads();
    if (t < NBK) {
        gbase[t] = atomicAdd(&gcur[t], cnt[t]);
        cnt[t] = 0;  // becomes local cursor
    }
    __syncthreads();
#pragma unroll
    for (int it = 0; it < 4; it++) {
        int idx = it * 256 + t;
        if (idx < 1000) {
            int4 c = col4[q0 + idx];
            int4 r = row4[q0 + idx];
            int d, s, b, p;
            d = c.x; s = r.x; b = d >> BSH; p = atomicAdd(&cnt[b], 1);
            tmp[gbase[b] + p] = ((unsigned int)(d & 511) << 17) | (unsigned int)s;
            d = c.y; s = r.y; b = d >> BSH; p = atomicAdd(&cnt[b], 1);
            tmp[gbase[b] + p] = ((unsigned int)(d & 511) << 17) | (unsigned int)s;
            d = c.z; s = r.z; b = d >> BSH; p = atomicAdd(&cnt[b], 1);
            tmp[gbase[b] + p] = ((unsigned int)(d & 511) << 17) | (unsigned int)s;
            d = c.w; s = r.w; b = d >> BSH; p = atomicAdd(&cnt[b], 1);
            tmp[gbase[b] + p] = ((unsigned int)(d & 511) << 17) | (unsigned int)s;
        }
    }
}

// -------------------------------------------------------- per-bucket CSR
__global__ __launch_bounds__(256) void k_bucket(const unsigned int* __restrict__ tmp,
                                                const int* __restrict__ gcur,
                                                int* __restrict__ off,
                                                int* __restrict__ degw,
                                                float* __restrict__ dinv,
                                                int* __restrict__ csr_src) {
    __shared__ int cnt[512];
    __shared__ int loff[512];
    __shared__ int sh[256];
    int b = blockIdx.x, t = threadIdx.x;
    int j0 = b << BSH;
    int nd = min(512, NN - j0);
    int rb = b * SLOT;
    int m = gcur[b] - rb;
    cnt[t] = 0; cnt[t + 256] = 0;
    __syncthreads();
    for (int i = t; i < m; i += 256)
        atomicAdd(&cnt[tmp[rb + i] >> 17], 1);
    __syncthreads();
    int r0 = cnt[2 * t], r1 = cnt[2 * t + 1];
    int p0 = (r0 + 3) & ~3, p1 = (r1 + 3) & ~3;  // pad to 4-entry alignment
    int ts = p0 + p1;
    sh[t] = ts;
    __syncthreads();
    for (int d = 1; d < 256; d <<= 1) {
        int u = (t >= d) ? sh[t - d] : 0;
        __syncthreads();
        sh[t] += u;
        __syncthreads();
    }
    int ex = sh[t] - ts;
    loff[2 * t] = ex;
    loff[2 * t + 1] = ex + p0;
    __syncthreads();
    for (int j = t; j < nd; j += 256) {
        int o = rb + loff[j];
        int dg = cnt[j];
        off[j0 + j] = o;
        degw[j0 + j] = dg;
        dinv[j0 + j] = rsqrtf((float)(dg + 1));  // +1 self-loop
        cnt[j] = o;  // becomes cursor
    }
    __syncthreads();
    for (int i = t; i < m; i += 256) {
        unsigned int e = tmp[rb + i];
        int d = e >> 17;
        int s = (int)(e & 0x1FFFFu);
        int p = atomicAdd(&cnt[d], 1);
        csr_src[p] = s;
    }
}

// ---------------------------------------------------------------- MFMA GEMM
// Hs[r][c] = dinv[r] * sum_k A[r][k] * Wt[c][k]
// Staging + fragment reads as R6/R8 (verified). NEW: LDS-transpose epilogue —
// acc -> LDS bf16 tile (row stride 136 shorts, 16B-aligned) -> coalesced
// uint4 global stores (8 per thread instead of 64 scalar shorts).
template <bool AF32>
__global__ __launch_bounds__(256) void k_gemm(const void* __restrict__ Ap,
                                              const unsigned short* __restrict__ Wt,
                                              const float* __restrict__ dinv,
                                              unsigned short* __restrict__ Hs) {
    __shared__ __align__(16) unsigned short Ws[128 * 136];  // 34 KB (staging uses 32 KB)
    int t = threadIdx.x;
    // stage Wt swizzled (R6-verified layout)
#pragma unroll
    for (int i = 0; i < 8; i++) {
        int id = t + i * 256;
        int n = id >> 4, c = id & 15;
        *(short8*)((char*)Ws + n * 256 + ((c ^ (n & 15)) << 4)) =
            *(const short8*)(Wt + n * 128 + c * 8);
    }
    __syncthreads();

    int lane = t & 63, wid = t >> 6;
    int n16 = lane & 15, quad = lane >> 4;
    int row_base = blockIdx.x * 128 + wid * 32;

    short8 a[2][4];
#pragma unroll
    for (int rt = 0; rt < 2; rt++) {
        int r = row_base + rt * 16 + n16;
        if (r > NN - 1) r = NN - 1;
        if (AF32) {
            const float* ap = (const float*)Ap + (size_t)r * 128 + quad * 8;
#pragma unroll
            for (int ks = 0; ks < 4; ks++) {
                float4 v0 = *(const float4*)(ap + ks * 32);
                float4 v1 = *(const float4*)(ap + ks * 32 + 4);
                uint4 up;
                up.x = pack2(v0.x, v0.y); up.y = pack2(v0.z, v0.w);
                up.z = pack2(v1.x, v1.y); up.w = pack2(v1.z, v1.w);
                a[rt][ks] = *(short8*)&up;
            }
        } else {
            const unsigned short* ap = (const unsigned short*)Ap + (size_t)r * 128 + quad * 8;
#pragma unroll
            for (int ks = 0; ks < 4; ks++)
                a[rt][ks] = *(const short8*)(ap + ks * 32);
        }
    }

    f32x4 acc[2][8];
#pragma unroll
    for (int rt = 0; rt < 2; rt++)
#pragma unroll
        for (int ct = 0; ct < 8; ct++)
            acc[rt][ct] = (f32x4){0.f, 0.f, 0.f, 0.f};

#pragma unroll
    for (int ks = 0; ks < 4; ks++) {
#pragma unroll
        for (int ct = 0; ct < 8; ct++) {
            short8 b = *(const short8*)((const char*)Ws +
                        (ct * 16 + n16) * 256 + ((((ks << 2) + quad) ^ n16) << 4));
            acc[0][ct] = __builtin_amdgcn_mfma_f32_16x16x32_bf16(a[0][ks], b, acc[0][ct], 0, 0, 0);
            acc[1][ct] = __builtin_amdgcn_mfma_f32_16x16x32_bf16(a[1][ks], b, acc[1][ct], 0, 0, 0);
        }
    }

    __syncthreads();  // all Ws B-frag reads done; safe to reuse as transpose tile

    // scatter acc into LDS tile: local row rl = wid*32 + rt*16 + quad*4 + reg,
    // col = ct*16 + n16. Row stride 136 shorts keeps uint4 rows 16B-aligned.
#pragma unroll
    for (int rt = 0; rt < 2; rt++) {
#pragma unroll
        for (int reg = 0; reg < 4; reg++) {
            int rl = wid * 32 + rt * 16 + quad * 4 + reg;
            int row = blockIdx.x * 128 + rl;
            float di = (row < NN) ? dinv[row] : 0.f;
#pragma unroll
            for (int ct = 0; ct < 8; ct++)
                Ws[rl * 136 + ct * 16 + n16] = f2b(acc[rt][ct][reg] * di);
        }
    }
    // wave-private strip readback (no block barrier needed): coalesced stores
#pragma unroll
    for (int i = 0; i < 8; i++) {
        int rl = wid * 32 + i * 4 + (lane >> 4);
        int row = blockIdx.x * 128 + rl;
        if (row < NN)
            *(uint4*)(Hs + (size_t)row * 128 + (lane & 15) * 8) =
                *(const uint4*)(Ws + rl * 136 + (lane & 15) * 8);
    }
}

// ---------------------------------------------------------------- aggregation
// out[i] = relu( dinv[i] * (Hs[i] + sum_e Hs[src_e]) + bias ), bf16 out.
// (R8-frozen: 4 subgroups x 16 lanes, 16 edges/iter, int4 index loads)
__global__ __launch_bounds__(256) void k_agg(const uint4* __restrict__ H4,
                                             const int* __restrict__ off,
                                             const int* __restrict__ degw,
                                             const int* __restrict__ csr_src,
                                             const float* __restrict__ dinv,
                                             const float* __restrict__ bias,
                                             uint4* __restrict__ out4) {
    int node = blockIdx.x * 4 + (threadIdx.x >> 6);
    int lane = threadIdx.x & 63;
    int sub = lane >> 4, li = lane & 15;
    float2 A0 = {0.f, 0.f}, A1 = {0.f, 0.f}, A2 = {0.f, 0.f}, A3 = {0.f, 0.f};
    if (sub == 0) {  // self term (already dinv-scaled)
        uint4 v = H4[(size_t)node * 16 + li];
        A0.x = bf_lo(v.x); A0.y = bf_hi(v.x); A1.x = bf_lo(v.y); A1.y = bf_hi(v.y);
        A2.x = bf_lo(v.z); A2.y = bf_hi(v.z); A3.x = bf_lo(v.w); A3.y = bf_hi(v.w);
    }
    int e0 = off[node], e1 = e0 + degw[node];
    int e = e0;
    for (; e + 16 <= e1; e += 16) {
        int4 sv = *(const int4*)(csr_src + e + sub * 4);
        uint4 w0 = H4[(size_t)sv.x * 16 + li];
        uint4 w1 = H4[(size_t)sv.y * 16 + li];
        uint4 w2 = H4[(size_t)sv.z * 16 + li];
        uint4 w3 = H4[(size_t)sv.w * 16 + li];
        A0.x += (bf_lo(w0.x) + bf_lo(w1.x)) + (bf_lo(w2.x) + bf_lo(w3.x));
        A0.y += (bf_hi(w0.x) + bf_hi(w1.x)) + (bf_hi(w2.x) + bf_hi(w3.x));
        A1.x += (bf_lo(w0.y) + bf_lo(w1.y)) + (bf_lo(w2.y) + bf_lo(w3.y));
        A1.y += (bf_hi(w0.y) + bf_hi(w1.y)) + (bf_hi(w2.y) + bf_hi(w3.y));
        A2.x += (bf_lo(w0.z) + bf_lo(w1.z)) + (bf_lo(w2.z) + bf_lo(w3.z));
        A2.y += (bf_hi(w0.z) + bf_hi(w1.z)) + (bf_hi(w2.z) + bf_hi(w3.z));
        A3.x += (bf_lo(w0.w) + bf_lo(w1.w)) + (bf_lo(w2.w) + bf_lo(w3.w));
        A3.y += (bf_hi(w0.w) + bf_hi(w1.w)) + (bf_hi(w2.w) + bf_hi(w3.w));
    }
    for (; e + 8 <= e1; e += 8) {
        int2 sv = *(const int2*)(csr_src + e + sub * 2);
        uint4 wA = H4[(size_t)sv.x * 16 + li];
        uint4 wB = H4[(size_t)sv.y * 16 + li];
        A0.x += bf_lo(wA.x) + bf_lo(wB.x); A0.y += bf_hi(wA.x) + bf_hi(wB.x);
        A1.x += bf_lo(wA.y) + bf_lo(wB.y); A1.y += bf_hi(wA.y) + bf_hi(wB.y);
        A2.x += bf_lo(wA.z) + bf_lo(wB.z); A2.y += bf_hi(wA.z) + bf_hi(wB.z);
        A3.x += bf_lo(wA.w) + bf_lo(wB.w); A3.y += bf_hi(wA.w) + bf_hi(wB.w);
    }
    for (; e < e1; e += 4) {
        int ee = e + sub;
        if (ee < e1) {
            int s = csr_src[ee];
            uint4 w = H4[(size_t)s * 16 + li];
            A0.x += bf_lo(w.x); A0.y += bf_hi(w.x);
            A1.x += bf_lo(w.y); A1.y += bf_hi(w.y);
            A2.x += bf_lo(w.z); A2.y += bf_hi(w.z);
            A3.x += bf_lo(w.w); A3.y += bf_hi(w.w);
        }
    }
#pragma unroll
    for (int d = 16; d <= 32; d <<= 1) {
        A0.x += __shfl_xor(A0.x, d); A0.y += __shfl_xor(A0.y, d);
        A1.x += __shfl_xor(A1.x, d); A1.y += __shfl_xor(A1.y, d);
        A2.x += __shfl_xor(A2.x, d); A2.y += __shfl_xor(A2.y, d);
        A3.x += __shfl_xor(A3.x, d); A3.y += __shfl_xor(A3.y, d);
    }
    if (sub == 0) {
        float di = dinv[node];
        const float4* b4 = (const float4*)bias;
        float4 bA = b4[li * 2], bB = b4[li * 2 + 1];
        float r0 = fmaxf(fmaf(di, A0.x, bA.x), 0.f);
        float r1 = fmaxf(fmaf(di, A0.y, bA.y), 0.f);
        float r2 = fmaxf(fmaf(di, A1.x, bA.z), 0.f);
        float r3 = fmaxf(fmaf(di, A1.y, bA.w), 0.f);
        float r4 = fmaxf(fmaf(di, A2.x, bB.x), 0.f);
        float r5 = fmaxf(fmaf(di, A2.y, bB.y), 0.f);
        float r6 = fmaxf(fmaf(di, A3.x, bB.z), 0.f);
        float r7 = fmaxf(fmaf(di, A3.y, bB.w), 0.f);
        uint4 o;
        o.x = pack2(r0, r1); o.y = pack2(r2, r3);
        o.z = pack2(r4, r5); o.w = pack2(r6, r7);
        out4[(size_t)node * 16 + li] = o;
    }
}

// ------------------------------------------------- fused mean-pool + head MLP
__global__ __launch_bounds__(256) void k_poolhead(const unsigned short* __restrict__ A,
                                                  const int* __restrict__ batch,
                                                  const float* __restrict__ u,
                                                  const float* __restrict__ Wh1,
                                                  const float* __restrict__ bh1,
                                                  const float* __restrict__ Wh2,
                                                  const float* __restrict__ bh2,
                                                  float* __restrict__ out) {
    int g = blockIdx.x, t = threadIdx.x;
    int lo = 0, hi = NN;
    while (lo < hi) { int m = (lo + hi) >> 1; if (batch[m] < g) lo = m + 1; else hi = m; }
    int start = lo;
    hi = NN;
    while (lo < hi) { int m = (lo + hi) >> 1; if (batch[m] < g + 1) lo = m + 1; else hi = m; }
    int end = lo;

    int li = t & 15;   // col chunk (8 cols)
    int ri = t >> 4;   // row offset 0..15
    float acc[8] = {0.f, 0.f, 0.f, 0.f, 0.f, 0.f, 0.f, 0.f};
    for (int i = start + ri; i < end; i += 16) {
        uint4 v = *(const uint4*)(A + (size_t)i * 128 + li * 8);
        acc[0] += bf_lo(v.x); acc[1] += bf_hi(v.x);
        acc[2] += bf_lo(v.y); acc[3] += bf_hi(v.y);
        acc[4] += bf_lo(v.z); acc[5] += bf_hi(v.z);
        acc[6] += bf_lo(v.w); acc[7] += bf_hi(v.w);
    }
#pragma unroll
    for (int j = 0; j < 8; j++) {
        acc[j] += __shfl_xor(acc[j], 16);
        acc[j] += __shfl_xor(acc[j], 32);
    }
    __shared__ float part[4][128];
    __shared__ float hc[192];
    __shared__ float tt[128];
    int w = t >> 6;
    if ((t & 63) < 16) {
#pragma unroll
        for (int j = 0; j < 8; j++) part[w][li * 8 + j] = acc[j];
    }
    __syncthreads();
    float cntf = (float)max(end - start, 1);
    if (t < 128) {
        hc[t] = (part[0][t] + part[1][t] + part[2][t] + part[3][t]) / cntf;
    } else if (t < 192) {
        hc[t] = u[g * 64 + (t - 128)];
    }
    __syncthreads();
    if (t < 128) {
        float a2 = bh1[t];
        for (int k = 0; k < 192; k++) a2 = fmaf(hc[k], Wh1[k * 128 + t], a2);
        tt[t] = fmaxf(a2, 0.f);
    }
    __syncthreads();
    if (t < 2) {
        float o = bh2[t];
        for (int c2 = 0; c2 < 128; c2++) o = fmaf(tt[c2], Wh2[c2 * 2 + t], o);
        out[g * 2 + t] = o;
    }
}

// ---------------------------------------------------------------- launcher
extern "C" void kernel_launch(void* const* d_in, const int* in_sizes, int n_in,
                              void* d_out, int out_size, void* d_ws, size_t ws_size,
                              hipStream_t stream) {
    const float* x   = (const float*)d_in[0];
    const int*   ei  = (const int*)d_in[1];
    const int*   row = ei;        // edge_index[0] = src
    const int*   col = ei + NE;   // edge_index[1] = dst
    const float* u   = (const float*)d_in[2];
    const int*   batch = (const int*)d_in[3];
    const float* W1  = (const float*)d_in[5];
    const float* b1  = (const float*)d_in[6];
    const float* W2  = (const float*)d_in[7];
    const float* b2  = (const float*)d_in[8];
    const float* Wh1 = (const float*)d_in[9];
    const float* bh1 = (const float*)d_in[10];
    const float* Wh2 = (const float*)d_in[11];
    const float* bh2 = (const float*)d_in[12];
    float* out = (float*)d_out;

    char* ws = (char*)d_ws;
    size_t o = 0;
    auto alloc = [&](size_t bytes) -> void* {
        void* p = ws + o;
        o += (bytes + 511) & ~(size_t)511;
        return p;
    };
    unsigned short* Hsb = (unsigned short*)alloc((size_t)NN * 128 * 2);
    unsigned short* A1b = (unsigned short*)alloc((size_t)NN * 128 * 2);
    unsigned short* A2b = (unsigned short*)alloc((size_t)NN * 128 * 2);
    unsigned short* Wt1 = (unsigned short*)alloc((size_t)128 * 128 * 2);
    unsigned short* Wt2 = (unsigned short*)alloc((size_t)128 * 128 * 2);
    float* dinv   = (float*)alloc((size_t)NN * 4);
    int*   off    = (int*)alloc((size_t)NN * 4);
    int*   degw   = (int*)alloc((size_t)NN * 4);
    int*   csr_src= (int*)alloc((size_t)NBK * SLOT * 4);
    unsigned int* tmp = (unsigned int*)alloc((size_t)NBK * SLOT * 4);
    int*   gcur   = (int*)alloc((size_t)256 * 4);

    // --- prep (W transpose + cursors) & CSR build ---
    k_prep<<<129, 256, 0, stream>>>(W1, W2, Wt1, Wt2, gcur);
    k_bin2<<<400, 256, 0, stream>>>(row, col, gcur, tmp);
    k_bucket<<<NBK, 256, 0, stream>>>(tmp, gcur, off, degw, dinv, csr_src);

    // --- layer 1 (f32 input, in-register bf16 pack) ---
    k_gemm<true><<<cdiv(NN, 128), 256, 0, stream>>>((const void*)x, Wt1, dinv, Hsb);
    k_agg<<<NN / 4, 256, 0, stream>>>((const uint4*)Hsb, off, degw, csr_src,
                                      dinv, b1, (uint4*)A1b);
    // --- layer 2 ---
    k_gemm<false><<<cdiv(NN, 128), 256, 0, stream>>>((const void*)A1b, Wt2, dinv, Hsb);
    k_agg<<<NN / 4, 256, 0, stream>>>((const uint4*)Hsb, off, degw, csr_src,
                                      dinv, b2, (uint4*)A2b);

    // --- fused mean pool + head ---
    k_poolhead<<<NG, 256, 0, stream>>>(A2b, batch, u, Wh1, bh1, Wh2, bh2, out);
}

// Round 12
// 294.620 us; speedup vs baseline: 2.1887x; 1.1335x over previous
//
#include <hip/hip_runtime.h>
#include <hip/hip_bf16.h>

#define NN 100000   // nodes
#define NE 1600000  // edges
#define NG 1000     // graphs
#define NBK 196     // dst buckets of 512 nodes (196*512 >= NN)
#define BSH 9       // bucket shift
#define SLOT 10240  // slack region per bucket (mean 8192 + 4-align padding)

typedef short short8 __attribute__((ext_vector_type(8)));
typedef float f32x4 __attribute__((ext_vector_type(4)));
typedef float f32x2 __attribute__((ext_vector_type(2)));

static inline int cdiv(int a, int b) { return (a + b - 1) / b; }

// f32 -> bf16 (RNE) and helpers
__device__ __forceinline__ unsigned short f2b(float f) {
    unsigned int u = __float_as_uint(f);
    u += 0x7fff + ((u >> 16) & 1);
    return (unsigned short)(u >> 16);
}
__device__ __forceinline__ unsigned int pack2(float lo, float hi) {
    return (unsigned int)f2b(lo) | ((unsigned int)f2b(hi) << 16);
}

// fp8 e4m3 (OCP) hardware converts; word select must be an immediate constant
template <int W>
__device__ __forceinline__ f32x2 f8_2f(unsigned int v) {
    return __builtin_amdgcn_cvt_pk_f32_fp8((int)v, W);
}
__device__ __forceinline__ unsigned int f2f8_lo(float a, float b, unsigned int old) {
    return (unsigned int)__builtin_amdgcn_cvt_pk_fp8_f32(a, b, (int)old, false);
}
__device__ __forceinline__ unsigned int f2f8_hi(float a, float b, unsigned int old) {
    return (unsigned int)__builtin_amdgcn_cvt_pk_fp8_f32(a, b, (int)old, true);
}

// ------------------------------------------------- prep: W transpose + cursors + permuted biases
// Permuted byte order for fp8 rows: byte q holds col (q&7)*16 + (q>>3).
__global__ __launch_bounds__(256) void k_prep(const float* __restrict__ W1,
                                              const float* __restrict__ W2,
                                              const float* __restrict__ b1,
                                              const float* __restrict__ b2,
                                              unsigned short* __restrict__ Wt1,
                                              unsigned short* __restrict__ Wt2,
                                              float* __restrict__ b1p,
                                              float* __restrict__ b2p,
                                              int* __restrict__ gcur) {
    int b = blockIdx.x, t = threadIdx.x;
    if (b < 128) {
        if (t < 128) Wt1[b * 128 + t] = f2b(W1[t * 128 + b]);
        else         Wt2[b * 128 + (t - 128)] = f2b(W2[(t - 128) * 128 + b]);
    } else {
        if (t < NBK) gcur[t] = t * SLOT;
        if (t < 128) {
            int c = (t & 7) * 16 + (t >> 3);  // col held at permuted position t
            b1p[t] = b1[c];
            b2p[t] = b2[c];
        }
    }
}

// -------------------------------------------------------- two-phase binning
__global__ __launch_bounds__(256) void k_bin2(const int* __restrict__ row,
                                              const int* __restrict__ col,
                                              int* __restrict__ gcur,
                                              unsigned int* __restrict__ tmp) {
    __shared__ int cnt[NBK];
    __shared__ int gbase[NBK];
    int t = threadIdx.x;
    if (t < NBK) cnt[t] = 0;
    __syncthreads();
    const int q0 = blockIdx.x * 1000;  // int4 index base (4000 edges)
    const int4* col4 = (const int4*)col;
    const int4* row4 = (const int4*)row;
#pragma unroll
    for (int it = 0; it < 4; it++) {
        int idx = it * 256 + t;
        if (idx < 1000) {
            int4 c = col4[q0 + idx];
            atomicAdd(&cnt[c.x >> BSH], 1);
            atomicAdd(&cnt[c.y >> BSH], 1);
            atomicAdd(&cnt[c.z >> BSH], 1);
            atomicAdd(&cnt[c.w >> BSH], 1);
        }
    }
    __syncthreads();
    if (t < NBK) {
        gbase[t] = atomicAdd(&gcur[t], cnt[t]);
        cnt[t] = 0;  // becomes local cursor
    }
    __syncthreads();
#pragma unroll
    for (int it = 0; it < 4; it++) {
        int idx = it * 256 + t;
        if (idx < 1000) {
            int4 c = col4[q0 + idx];
            int4 r = row4[q0 + idx];
            int d, s, b, p;
            d = c.x; s = r.x; b = d >> BSH; p = atomicAdd(&cnt[b], 1);
            tmp[gbase[b] + p] = ((unsigned int)(d & 511) << 17) | (unsigned int)s;
            d = c.y; s = r.y; b = d >> BSH; p = atomicAdd(&cnt[b], 1);
            tmp[gbase[b] + p] = ((unsigned int)(d & 511) << 17) | (unsigned int)s;
            d = c.z; s = r.z; b = d >> BSH; p = atomicAdd(&cnt[b], 1);
            tmp[gbase[b] + p] = ((unsigned int)(d & 511) << 17) | (unsigned int)s;
            d = c.w; s = r.w; b = d >> BSH; p = atomicAdd(&cnt[b], 1);
            tmp[gbase[b] + p] = ((unsigned int)(d & 511) << 17) | (unsigned int)s;
        }
    }
}

// -------------------------------------------------------- per-bucket CSR
__global__ __launch_bounds__(256) void k_bucket(const unsigned int* __restrict__ tmp,
                                                const int* __restrict__ gcur,
                                                int* __restrict__ off,
                                                int* __restrict__ degw,
                                                float* __restrict__ dinv,
                                                int* __restrict__ csr_src) {
    __shared__ int cnt[512];
    __shared__ int loff[512];
    __shared__ int sh[256];
    int b = blockIdx.x, t = threadIdx.x;
    int j0 = b << BSH;
    int nd = min(512, NN - j0);
    int rb = b * SLOT;
    int m = gcur[b] - rb;
    cnt[t] = 0; cnt[t + 256] = 0;
    __syncthreads();
    for (int i = t; i < m; i += 256)
        atomicAdd(&cnt[tmp[rb + i] >> 17], 1);
    __syncthreads();
    int r0 = cnt[2 * t], r1 = cnt[2 * t + 1];
    int p0 = (r0 + 3) & ~3, p1 = (r1 + 3) & ~3;  // pad to 4-entry alignment
    int ts = p0 + p1;
    sh[t] = ts;
    __syncthreads();
    for (int d = 1; d < 256; d <<= 1) {
        int u = (t >= d) ? sh[t - d] : 0;
        __syncthreads();
        sh[t] += u;
        __syncthreads();
    }
    int ex = sh[t] - ts;
    loff[2 * t] = ex;
    loff[2 * t + 1] = ex + p0;
    __syncthreads();
    for (int j = t; j < nd; j += 256) {
        int o = rb + loff[j];
        int dg = cnt[j];
        off[j0 + j] = o;
        degw[j0 + j] = dg;
        dinv[j0 + j] = rsqrtf((float)(dg + 1));  // +1 self-loop
        cnt[j] = o;  // becomes cursor
    }
    __syncthreads();
    for (int i = t; i < m; i += 256) {
        unsigned int e = tmp[rb + i];
        int d = e >> 17;
        int s = (int)(e & 0x1FFFFu);
        int p = atomicAdd(&cnt[d], 1);
        csr_src[p] = s;
    }
}

// ---------------------------------------------------------------- MFMA GEMM
// Hs8[r] = fp8( dinv[r] * (A @ Wt^T) row r ), PERMUTED byte order (q=n16*8+ct).
// Staging + fragment reads: R6/R8-verified. Epilogue: registers-only fp8 pack,
// one uint2 (8B) coalesced store per row-fragment per lane.
template <bool AF32>
__global__ __launch_bounds__(256) void k_gemm(const void* __restrict__ Ap,
                                              const unsigned short* __restrict__ Wt,
                                              const float* __restrict__ dinv,
                                              unsigned char* __restrict__ Hs8) {
    __shared__ __align__(16) unsigned short Ws[128 * 128];  // 32 KB
    int t = threadIdx.x;
#pragma unroll
    for (int i = 0; i < 8; i++) {
        int id = t + i * 256;
        int n = id >> 4, c = id & 15;
        *(short8*)((char*)Ws + n * 256 + ((c ^ (n & 15)) << 4)) =
            *(const short8*)(Wt + n * 128 + c * 8);
    }
    __syncthreads();

    int lane = t & 63, wid = t >> 6;
    int n16 = lane & 15, quad = lane >> 4;
    int row_base = blockIdx.x * 128 + wid * 32;

    short8 a[2][4];
#pragma unroll
    for (int rt = 0; rt < 2; rt++) {
        int r = row_base + rt * 16 + n16;
        if (r > NN - 1) r = NN - 1;
        if (AF32) {
            const float* ap = (const float*)Ap + (size_t)r * 128 + quad * 8;
#pragma unroll
            for (int ks = 0; ks < 4; ks++) {
                float4 v0 = *(const float4*)(ap + ks * 32);
                float4 v1 = *(const float4*)(ap + ks * 32 + 4);
                uint4 up;
                up.x = pack2(v0.x, v0.y); up.y = pack2(v0.z, v0.w);
                up.z = pack2(v1.x, v1.y); up.w = pack2(v1.z, v1.w);
                a[rt][ks] = *(short8*)&up;
            }
        } else {
            const unsigned short* ap = (const unsigned short*)Ap + (size_t)r * 128 + quad * 8;
#pragma unroll
            for (int ks = 0; ks < 4; ks++)
                a[rt][ks] = *(const short8*)(ap + ks * 32);
        }
    }

    f32x4 acc[2][8];
#pragma unroll
    for (int rt = 0; rt < 2; rt++)
#pragma unroll
        for (int ct = 0; ct < 8; ct++)
            acc[rt][ct] = (f32x4){0.f, 0.f, 0.f, 0.f};

#pragma unroll
    for (int ks = 0; ks < 4; ks++) {
#pragma unroll
        for (int ct = 0; ct < 8; ct++) {
            short8 b = *(const short8*)((const char*)Ws +
                        (ct * 16 + n16) * 256 + ((((ks << 2) + quad) ^ n16) << 4));
            acc[0][ct] = __builtin_amdgcn_mfma_f32_16x16x32_bf16(a[0][ks], b, acc[0][ct], 0, 0, 0);
            acc[1][ct] = __builtin_amdgcn_mfma_f32_16x16x32_bf16(a[1][ks], b, acc[1][ct], 0, 0, 0);
        }
    }

    // epilogue: thread holds cols ct*16+n16 of row -> permuted bytes n16*8+ct
#pragma unroll
    for (int rt = 0; rt < 2; rt++) {
#pragma unroll
        for (int reg = 0; reg < 4; reg++) {
            int row = row_base + rt * 16 + quad * 4 + reg;
            if (row < NN) {
                float di = dinv[row];
                unsigned int u0 = 0, u1 = 0;
                u0 = f2f8_lo(acc[rt][0][reg] * di, acc[rt][1][reg] * di, u0);
                u0 = f2f8_hi(acc[rt][2][reg] * di, acc[rt][3][reg] * di, u0);
                u1 = f2f8_lo(acc[rt][4][reg] * di, acc[rt][5][reg] * di, u1);
                u1 = f2f8_hi(acc[rt][6][reg] * di, acc[rt][7][reg] * di, u1);
                uint2 o; o.x = u0; o.y = u1;
                ((uint2*)(Hs8 + (size_t)row * 128))[n16] = o;
            }
        }
    }
}

// ---------------------------------------------------------------- aggregation
// out[i] = relu( dinv[i] * (Hs[i] + sum_e Hs[src_e]) + bias )
// Hs rows: fp8 permuted, 128B (one line). Structure identical to R8:
// 4 subgroups x 16 lanes, 16 edges/iter via int4 index loads; uint2 gathers.
// FP8OUT: layer2 writes fp8-permuted A2; else bf16-natural A1 (for GEMM2).
template <bool FP8OUT>
__global__ __launch_bounds__(256) void k_agg(const uint2* __restrict__ H2,
                                             const int* __restrict__ off,
                                             const int* __restrict__ degw,
                                             const int* __restrict__ csr_src,
                                             const float* __restrict__ dinv,
                                             const float* __restrict__ biasp,
                                             void* __restrict__ outp) {
    int node = blockIdx.x * 4 + (threadIdx.x >> 6);
    int lane = threadIdx.x & 63;
    int sub = lane >> 4, li = lane & 15;
    float2 A0 = {0.f, 0.f}, A1 = {0.f, 0.f}, A2 = {0.f, 0.f}, A3 = {0.f, 0.f};
    f32x2 p;
#define ACC8(w) { \
        p = f8_2f<0>((w).x); A0.x += p.x; A0.y += p.y; \
        p = f8_2f<1>((w).x); A1.x += p.x; A1.y += p.y; \
        p = f8_2f<0>((w).y); A2.x += p.x; A2.y += p.y; \
        p = f8_2f<1>((w).y); A3.x += p.x; A3.y += p.y; }
    if (sub == 0) {  // self term (already dinv-scaled)
        uint2 v = H2[(size_t)node * 16 + li];
        ACC8(v)
    }
    int e0 = off[node], e1 = e0 + degw[node];
    int e = e0;
    for (; e + 16 <= e1; e += 16) {
        int4 sv = *(const int4*)(csr_src + e + sub * 4);
        uint2 w0 = H2[(size_t)sv.x * 16 + li];
        uint2 w1 = H2[(size_t)sv.y * 16 + li];
        uint2 w2 = H2[(size_t)sv.z * 16 + li];
        uint2 w3 = H2[(size_t)sv.w * 16 + li];
        ACC8(w0) ACC8(w1) ACC8(w2) ACC8(w3)
    }
    for (; e + 8 <= e1; e += 8) {
        int2 sv = *(const int2*)(csr_src + e + sub * 2);
        uint2 wA = H2[(size_t)sv.x * 16 + li];
        uint2 wB = H2[(size_t)sv.y * 16 + li];
        ACC8(wA) ACC8(wB)
    }
    for (; e < e1; e += 4) {
        int ee = e + sub;
        if (ee < e1) {
            int s = csr_src[ee];
            uint2 w = H2[(size_t)s * 16 + li];
            ACC8(w)
        }
    }
#undef ACC8
#pragma unroll
    for (int d = 16; d <= 32; d <<= 1) {
        A0.x += __shfl_xor(A0.x, d); A0.y += __shfl_xor(A0.y, d);
        A1.x += __shfl_xor(A1.x, d); A1.y += __shfl_xor(A1.y, d);
        A2.x += __shfl_xor(A2.x, d); A2.y += __shfl_xor(A2.y, d);
        A3.x += __shfl_xor(A3.x, d); A3.y += __shfl_xor(A3.y, d);
    }
    if (sub == 0) {
        float di = dinv[node];
        const float4* b4 = (const float4*)biasp;  // permuted bias
        float4 bA = b4[li * 2], bB = b4[li * 2 + 1];
        float r0 = fmaxf(fmaf(di, A0.x, bA.x), 0.f);  // col  0+li
        float r1 = fmaxf(fmaf(di, A0.y, bA.y), 0.f);  // col 16+li
        float r2 = fmaxf(fmaf(di, A1.x, bA.z), 0.f);
        float r3 = fmaxf(fmaf(di, A1.y, bA.w), 0.f);
        float r4 = fmaxf(fmaf(di, A2.x, bB.x), 0.f);
        float r5 = fmaxf(fmaf(di, A2.y, bB.y), 0.f);
        float r6 = fmaxf(fmaf(di, A3.x, bB.z), 0.f);
        float r7 = fmaxf(fmaf(di, A3.y, bB.w), 0.f);
        if (FP8OUT) {  // fp8 permuted (8B packed store)
            unsigned int u0 = 0, u1 = 0;
            u0 = f2f8_lo(r0, r1, u0); u0 = f2f8_hi(r2, r3, u0);
            u1 = f2f8_lo(r4, r5, u1); u1 = f2f8_hi(r6, r7, u1);
            uint2 o; o.x = u0; o.y = u1;
            ((uint2*)outp)[(size_t)node * 16 + li] = o;
        } else {  // bf16 natural (for GEMM2 A-frags)
            unsigned short* ob = (unsigned short*)outp + (size_t)node * 128 + li;
            ob[0]   = f2b(r0); ob[16]  = f2b(r1); ob[32]  = f2b(r2); ob[48]  = f2b(r3);
            ob[64]  = f2b(r4); ob[80]  = f2b(r5); ob[96]  = f2b(r6); ob[112] = f2b(r7);
        }
    }
}

// ------------------------------------------------- fused mean-pool + head MLP
// A2: fp8 permuted. part[] indexed by permuted byte q; hc[] unpermutes.
__global__ __launch_bounds__(256) void k_poolhead(const unsigned char* __restrict__ A,
                                                  const int* __restrict__ batch,
                                                  const float* __restrict__ u,
                                                  const float* __restrict__ Wh1,
                                                  const float* __restrict__ bh1,
                                                  const float* __restrict__ Wh2,
                                                  const float* __restrict__ bh2,
                                                  float* __restrict__ out) {
    int g = blockIdx.x, t = threadIdx.x;
    int lo = 0, hi = NN;
    while (lo < hi) { int m = (lo + hi) >> 1; if (batch[m] < g) lo = m + 1; else hi = m; }
    int start = lo;
    hi = NN;
    while (lo < hi) { int m = (lo + hi) >> 1; if (batch[m] < g + 1) lo = m + 1; else hi = m; }
    int end = lo;

    int li = t & 7;    // 16-byte chunk of the 128B row
    int ri = t >> 3;   // row offset 0..31
    float acc[16];
#pragma unroll
    for (int j = 0; j < 16; j++) acc[j] = 0.f;
    f32x2 p;
    for (int i = start + ri; i < end; i += 32) {
        uint4 v = ((const uint4*)A)[(size_t)i * 8 + li];
#define UP(vv, base) p = f8_2f<0>(vv); acc[base] += p.x; acc[base+1] += p.y; \
                     p = f8_2f<1>(vv); acc[base+2] += p.x; acc[base+3] += p.y;
        UP(v.x, 0) UP(v.y, 4) UP(v.z, 8) UP(v.w, 12)
#undef UP
    }
#pragma unroll
    for (int j = 0; j < 16; j++) {
        acc[j] += __shfl_xor(acc[j], 8);
        acc[j] += __shfl_xor(acc[j], 16);
        acc[j] += __shfl_xor(acc[j], 32);
    }
    __shared__ float part[4][128];
    __shared__ float hc[192];
    __shared__ float tt[128];
    int w = t >> 6;
    if ((t & 63) < 8) {
#pragma unroll
        for (int j = 0; j < 16; j++) part[w][li * 16 + j] = acc[j];  // index = byte q
    }
    __syncthreads();
    float cntf = (float)max(end - start, 1);
    if (t < 128) {
        int q = (t & 15) * 8 + (t >> 4);  // permuted position of col t
        hc[t] = (part[0][q] + part[1][q] + part[2][q] + part[3][q]) / cntf;
    } else if (t < 192) {
        hc[t] = u[g * 64 + (t - 128)];
    }
    __syncthreads();
    if (t < 128) {
        float a2 = bh1[t];
        for (int k = 0; k < 192; k++) a2 = fmaf(hc[k], Wh1[k * 128 + t], a2);
        tt[t] = fmaxf(a2, 0.f);
    }
    __syncthreads();
    if (t < 2) {
        float o = bh2[t];
        for (int c2 = 0; c2 < 128; c2++) o = fmaf(tt[c2], Wh2[c2 * 2 + t], o);
        out[g * 2 + t] = o;
    }
}

// ---------------------------------------------------------------- launcher
extern "C" void kernel_launch(void* const* d_in, const int* in_sizes, int n_in,
                              void* d_out, int out_size, void* d_ws, size_t ws_size,
                              hipStream_t stream) {
    const float* x   = (const float*)d_in[0];
    const int*   ei  = (const int*)d_in[1];
    const int*   row = ei;        // edge_index[0] = src
    const int*   col = ei + NE;   // edge_index[1] = dst
    const float* u   = (const float*)d_in[2];
    const int*   batch = (const int*)d_in[3];
    const float* W1  = (const float*)d_in[5];
    const float* b1  = (const float*)d_in[6];
    const float* W2  = (const float*)d_in[7];
    const float* b2  = (const float*)d_in[8];
    const float* Wh1 = (const float*)d_in[9];
    const float* bh1 = (const float*)d_in[10];
    const float* Wh2 = (const float*)d_in[11];
    const float* bh2 = (const float*)d_in[12];
    float* out = (float*)d_out;

    char* ws = (char*)d_ws;
    size_t o = 0;
    auto alloc = [&](size_t bytes) -> void* {
        void* p = ws + o;
        o += (bytes + 511) & ~(size_t)511;
        return p;
    };
    unsigned char*  Hs8 = (unsigned char*)alloc((size_t)NN * 128);       // fp8 permuted
    unsigned short* A1b = (unsigned short*)alloc((size_t)NN * 128 * 2);  // bf16 natural
    unsigned char*  A2b = (unsigned char*)alloc((size_t)NN * 128);       // fp8 permuted
    unsigned short* Wt1 = (unsigned short*)alloc((size_t)128 * 128 * 2);
    unsigned short* Wt2 = (unsigned short*)alloc((size_t)128 * 128 * 2);
    float* b1p    = (float*)alloc((size_t)128 * 4);
    float* b2p    = (float*)alloc((size_t)128 * 4);
    float* dinv   = (float*)alloc((size_t)NN * 4);
    int*   off    = (int*)alloc((size_t)NN * 4);
    int*   degw   = (int*)alloc((size_t)NN * 4);
    int*   csr_src= (int*)alloc((size_t)NBK * SLOT * 4);
    unsigned int* tmp = (unsigned int*)alloc((size_t)NBK * SLOT * 4);
    int*   gcur   = (int*)alloc((size_t)256 * 4);

    // --- prep (W transpose + cursors + permuted biases) & CSR build ---
    k_prep<<<129, 256, 0, stream>>>(W1, W2, b1, b2, Wt1, Wt2, b1p, b2p, gcur);
    k_bin2<<<400, 256, 0, stream>>>(row, col, gcur, tmp);
    k_bucket<<<NBK, 256, 0, stream>>>(tmp, gcur, off, degw, dinv, csr_src);

    // --- layer 1 (f32 input, in-register bf16 pack; fp8 H) ---
    k_gemm<true><<<cdiv(NN, 128), 256, 0, stream>>>((const void*)x, Wt1, dinv, Hs8);
    k_agg<false><<<NN / 4, 256, 0, stream>>>((const uint2*)Hs8, off, degw, csr_src,
                                             dinv, b1p, (void*)A1b);
    // --- layer 2 ---
    k_gemm<false><<<cdiv(NN, 128), 256, 0, stream>>>((const void*)A1b, Wt2, dinv, Hs8);
    k_agg<true><<<NN / 4, 256, 0, stream>>>((const uint2*)Hs8, off, degw, csr_src,
                                            dinv, b2p, (void*)A2b);

    // --- fused mean pool + head ---
    k_poolhead<<<NG, 256, 0, stream>>>(A2b, batch, u, Wh1, bh1, Wh2, bh2, out);
}